// Round 3
// baseline (3142.856 us; speedup 1.0000x reference)
//
#include <hip/hip_runtime.h>

#define D 20
#define ACT 5
#define NEG_SLOPE 0.2f
#define PSTRIDE 24   // packed row stride in floats (96 B, float4-aligned)

__device__ __forceinline__ float leaky(float x) {
    return x > 0.f ? x : NEG_SLOPE * x;
}

// ---------------------------------------------------------------------------
// 1. h1p[i][0..19] = x[i] @ gcn_W   (packed stride-24 rows)
// ---------------------------------------------------------------------------
__global__ void k_xw(const float* __restrict__ x, const float* __restrict__ W,
                     float* __restrict__ h1p, int n) {
    __shared__ float sW[D * D];
    for (int t = threadIdx.x; t < D * D; t += blockDim.x) sW[t] = W[t];
    __syncthreads();
    int i = blockIdx.x * blockDim.x + threadIdx.x;
    if (i >= n) return;
    float xi[D];
    const float4* xr = (const float4*)(x + (size_t)i * D);
#pragma unroll
    for (int q = 0; q < D / 4; ++q) {
        float4 v = xr[q];
        xi[4 * q + 0] = v.x; xi[4 * q + 1] = v.y;
        xi[4 * q + 2] = v.z; xi[4 * q + 3] = v.w;
    }
    float4* hr = (float4*)(h1p + (size_t)i * PSTRIDE);
#pragma unroll
    for (int q = 0; q < D / 4; ++q) {
        float4 o;
        float* op = (float*)&o;
#pragma unroll
        for (int r = 0; r < 4; ++r) {
            int d = 4 * q + r;
            float acc = 0.f;
#pragma unroll
            for (int k = 0; k < D; ++k) acc += xi[k] * sW[k * D + d];
            op[r] = acc;
        }
        hr[q] = o;
    }
}

// ---------------------------------------------------------------------------
// 2. histogram of dst (real in-degree)
// ---------------------------------------------------------------------------
__global__ void k_hist(const int* __restrict__ dst, int* __restrict__ deg, int e) {
    int i = blockIdx.x * blockDim.x + threadIdx.x;
    if (i < e) atomicAdd(&deg[dst[i]], 1);
}

// ---------------------------------------------------------------------------
// 3. single-block: per-chunk partial sums -> base[256]; off[n] = total
// ---------------------------------------------------------------------------
__global__ void k_scan(const int* __restrict__ deg, int* __restrict__ base,
                       int* __restrict__ off_n, int n) {
    __shared__ int ssum[256];
    int t = threadIdx.x;
    int chunk = (n + 255) / 256;
    int lo = t * chunk, hi = min(lo + chunk, n);
    int s = 0;
    for (int i = lo; i < hi; ++i) s += deg[i];
    ssum[t] = s;
    __syncthreads();
    if (t == 0) {
        int run = 0;
        for (int k = 0; k < 256; ++k) { int v = ssum[k]; base[k] = run; run += v; }
        *off_n = run;
    }
}

// ---------------------------------------------------------------------------
// 4. per-chunk fill: off/cur + dinv packed into h1p[.][20]
// ---------------------------------------------------------------------------
__global__ void k_fill(const int* __restrict__ deg, const int* __restrict__ base,
                       int* __restrict__ off, int* __restrict__ cur,
                       float* __restrict__ h1p, int n) {
    __shared__ int sdeg[512];
    int b = blockIdx.x;
    int chunk = (n + 255) / 256;
    int lo = b * chunk, hi = min(lo + chunk, n);
    int len = hi - lo;
    for (int i = threadIdx.x; i < len; i += blockDim.x) {
        int dv = deg[lo + i];
        sdeg[i] = dv;
        h1p[(size_t)(lo + i) * PSTRIDE + 20] = rsqrtf((float)(dv + 1));
    }
    __syncthreads();
    if (threadIdx.x == 0) {
        int run = base[b];
        for (int i = 0; i < len; ++i) { int v = sdeg[i]; sdeg[i] = run; run += v; }
    }
    __syncthreads();
    for (int i = threadIdx.x; i < len; i += blockDim.x) {
        int o = sdeg[i];
        off[lo + i] = o;
        cur[lo + i] = o;
    }
}

// ---------------------------------------------------------------------------
// 5. scatter edges into CSR-by-dst (order within segment irrelevant)
// ---------------------------------------------------------------------------
__global__ void k_scatter(const int* __restrict__ src, const int* __restrict__ dst,
                          int* __restrict__ cur, int* __restrict__ esrc, int e) {
    int i = blockIdx.x * blockDim.x + threadIdx.x;
    if (i >= e) return;
    int p = atomicAdd(&cur[dst[i]], 1);
    esrc[p] = src[i];
}

// ---------------------------------------------------------------------------
// 6. fused GCN gather + relu + GAT node transform. 4 lanes per node.
//    reads h1p (row+dinv packed), writes h2p (row + a_s + a_d packed)
// ---------------------------------------------------------------------------
__global__ void k_gcn_gat(const int* __restrict__ off, const int* __restrict__ esrc,
                          const float* __restrict__ h1p, const float* __restrict__ gcn_b,
                          const float* __restrict__ gat_W, const float* __restrict__ att_s,
                          const float* __restrict__ att_d, float* __restrict__ h2p, int n) {
    __shared__ float sW[D * D], sb[D], sas[D], sad[D];
    for (int t = threadIdx.x; t < D * D; t += blockDim.x) sW[t] = gat_W[t];
    if (threadIdx.x < D) {
        sb[threadIdx.x]  = gcn_b[threadIdx.x];
        sas[threadIdx.x] = att_s[threadIdx.x];
        sad[threadIdx.x] = att_d[threadIdx.x];
    }
    __syncthreads();
    int t = threadIdx.x;
    int i = blockIdx.x * (blockDim.x >> 2) + (t >> 2);
    int q = t & 3;
    bool valid = i < n;

    float acc[D];
#pragma unroll
    for (int d = 0; d < D; ++d) acc[d] = 0.f;
    float di = 0.f;
    if (valid) {
        const float* row = h1p + (size_t)i * PSTRIDE;
        di = row[20];
        if (q == 0) {                       // self-loop term
            float c = di * di;
            const float4* hr = (const float4*)row;
#pragma unroll
            for (int qq = 0; qq < D / 4; ++qq) {
                float4 v = hr[qq];
                acc[4 * qq + 0] = c * v.x; acc[4 * qq + 1] = c * v.y;
                acc[4 * qq + 2] = c * v.z; acc[4 * qq + 3] = c * v.w;
            }
        }
        int s0 = off[i], s1 = off[i + 1];
        for (int j = s0 + q; j < s1; j += 4) {
            int s = esrc[j];
            const float* rs = h1p + (size_t)s * PSTRIDE;
            float norm = di * rs[20];
            const float4* hs = (const float4*)rs;
#pragma unroll
            for (int qq = 0; qq < D / 4; ++qq) {
                float4 v = hs[qq];
                acc[4 * qq + 0] += norm * v.x; acc[4 * qq + 1] += norm * v.y;
                acc[4 * qq + 2] += norm * v.z; acc[4 * qq + 3] += norm * v.w;
            }
        }
    }
    // quad all-reduce of acc
#pragma unroll
    for (int d = 0; d < D; ++d) acc[d] += __shfl_xor(acc[d], 1);
#pragma unroll
    for (int d = 0; d < D; ++d) acc[d] += __shfl_xor(acc[d], 2);

    float v[D];
#pragma unroll
    for (int k = 0; k < D; ++k) {
        float tv = acc[k] + sb[k];
        v[k] = tv > 0.f ? tv : 0.f;
    }
    // each lane computes 5 output channels d = q*5 + r
    float o5[5];
    float as_ = 0.f, ad_ = 0.f;
#pragma unroll
    for (int r = 0; r < 5; ++r) {
        int d = q * 5 + r;
        float a = 0.f;
#pragma unroll
        for (int k = 0; k < D; ++k) a += v[k] * sW[k * D + d];
        o5[r] = a;
        as_ += a * sas[d];
        ad_ += a * sad[d];
    }
    if (valid) {
        float* orow = h2p + (size_t)i * PSTRIDE + q * 5;
#pragma unroll
        for (int r = 0; r < 5; ++r) orow[r] = o5[r];
    }
    as_ += __shfl_xor(as_, 1); as_ += __shfl_xor(as_, 2);
    ad_ += __shfl_xor(ad_, 1); ad_ += __shfl_xor(ad_, 2);
    if (valid && q == 0) {
        h2p[(size_t)i * PSTRIDE + 20] = as_;
        h2p[(size_t)i * PSTRIDE + 21] = ad_;
    }
}

// ---------------------------------------------------------------------------
// 7. GAT online-softmax aggregate, 8 lanes per node, fused graph readout
// ---------------------------------------------------------------------------
__global__ void k_gat_agg(const int* __restrict__ off, const int* __restrict__ esrc,
                          const float* __restrict__ h2p, const float* __restrict__ gat_b,
                          float* __restrict__ g, int n) {
    __shared__ float sb[D];
    if (threadIdx.x < D) sb[threadIdx.x] = gat_b[threadIdx.x];
    __syncthreads();
    int t = threadIdx.x;
    int i = blockIdx.x * (blockDim.x >> 3) + (t >> 3);
    int o = t & 7;
    bool valid = i < n;

    float m = -1e30f, den = 0.f;
    float acc[D];
#pragma unroll
    for (int d = 0; d < D; ++d) acc[d] = 0.f;

    if (valid) {
        const float* row = h2p + (size_t)i * PSTRIDE;
        float ad_i = row[21];
        if (o == 0) {                      // self edge seeds the online softmax
            m = leaky(row[20] + ad_i);
            den = 1.f;
            const float4* hr = (const float4*)row;
#pragma unroll
            for (int qq = 0; qq < D / 4; ++qq) {
                float4 v = hr[qq];
                acc[4 * qq + 0] = v.x; acc[4 * qq + 1] = v.y;
                acc[4 * qq + 2] = v.z; acc[4 * qq + 3] = v.w;
            }
        }
        int s0 = off[i], s1 = off[i + 1];
        for (int j = s0 + o; j < s1; j += 8) {
            int s = esrc[j];
            const float* rs = h2p + (size_t)s * PSTRIDE;
            float eg = leaky(rs[20] + ad_i);
            float nm = fmaxf(m, eg);
            float c = __expf(m - nm), w = __expf(eg - nm);
            den = den * c + w;
            const float4* hs = (const float4*)rs;
#pragma unroll
            for (int qq = 0; qq < D / 4; ++qq) {
                float4 v = hs[qq];
                acc[4 * qq + 0] = acc[4 * qq + 0] * c + w * v.x;
                acc[4 * qq + 1] = acc[4 * qq + 1] * c + w * v.y;
                acc[4 * qq + 2] = acc[4 * qq + 2] * c + w * v.z;
                acc[4 * qq + 3] = acc[4 * qq + 3] * c + w * v.w;
            }
            m = nm;
        }
    }
    // octet merge of (m, den, acc)
#pragma unroll
    for (int mask = 1; mask < 8; mask <<= 1) {
        float om = __shfl_xor(m, mask);
        float oden = __shfl_xor(den, mask);
        float nm = fmaxf(m, om);
        float c1 = __expf(m - nm), c2 = __expf(om - nm);
        den = den * c1 + oden * c2;
#pragma unroll
        for (int d = 0; d < D; ++d) {
            float oa = __shfl_xor(acc[d], mask);
            acc[d] = acc[d] * c1 + oa * c2;
        }
        m = nm;
    }
    float inv = den > 0.f ? 1.0f / den : 0.f;
#pragma unroll
    for (int d = 0; d < D; ++d) {
        float vv = acc[d] * inv + sb[d];
        vv = vv > 0.f ? vv : 0.f;
        if (!valid || o != 0) vv = 0.f;    // one contribution per node
        acc[d] = vv;
    }
    // wave reduce each channel, one atomicAdd per wave per channel
#pragma unroll
    for (int d = 0; d < D; ++d) {
        float vv = acc[d];
        for (int s2 = 32; s2; s2 >>= 1) vv += __shfl_down(vv, s2);
        if ((t & 63) == 0) atomicAdd(&g[d], vv);
    }
}

// ---------------------------------------------------------------------------
// 8. dueling head
// ---------------------------------------------------------------------------
__global__ void k_head(const float* __restrict__ g,
                       const float* __restrict__ aW1, const float* __restrict__ ab1,
                       const float* __restrict__ aW2, const float* __restrict__ ab2,
                       const float* __restrict__ vW1, const float* __restrict__ vb1,
                       const float* __restrict__ vW2, const float* __restrict__ vb2,
                       float* __restrict__ out) {
    __shared__ float sg[D], t1[D], t2[D], A[ACT], V, meanA;
    int t = threadIdx.x;
    if (t < D) sg[t] = g[t];
    __syncthreads();
    if (t < D) {
        float a = ab1[t], v = vb1[t];
        for (int k = 0; k < D; ++k) {
            a += sg[k] * aW1[k * D + t];
            v += sg[k] * vW1[k * D + t];
        }
        t1[t] = a > 0.f ? a : 0.f;
        t2[t] = v > 0.f ? v : 0.f;
    }
    __syncthreads();
    if (t < ACT) {
        float a = ab2[t];
        for (int d = 0; d < D; ++d) a += t1[d] * aW2[d * ACT + t];
        A[t] = a;
    }
    if (t == D) {
        float v = vb2[0];
        for (int d = 0; d < D; ++d) v += t2[d] * vW2[d];
        V = v;
    }
    __syncthreads();
    if (t == 0) {
        float s = 0.f;
        for (int j = 0; j < ACT; ++j) s += A[j];
        meanA = s / ACT;
    }
    __syncthreads();
    if (t < ACT) out[t] = V + A[t] - meanA;
}

extern "C" void kernel_launch(void* const* d_in, const int* in_sizes, int n_in,
                              void* d_out, int out_size, void* d_ws, size_t ws_size,
                              hipStream_t stream) {
    const float* x      = (const float*)d_in[0];
    const int*   ei     = (const int*)d_in[1];
    // d_in[2] edge_attr: unused by the reference
    const float* gcn_W  = (const float*)d_in[3];
    const float* gcn_b  = (const float*)d_in[4];
    const float* gat_W  = (const float*)d_in[5];
    const float* att_s  = (const float*)d_in[6];
    const float* att_d  = (const float*)d_in[7];
    const float* gat_b  = (const float*)d_in[8];
    const float* aW1    = (const float*)d_in[9];
    const float* ab1    = (const float*)d_in[10];
    const float* aW2    = (const float*)d_in[11];
    const float* ab2    = (const float*)d_in[12];
    const float* vW1    = (const float*)d_in[13];
    const float* vb1    = (const float*)d_in[14];
    const float* vW2    = (const float*)d_in[15];
    const float* vb2    = (const float*)d_in[16];

    const int n = in_sizes[0] / D;       // 100000
    const int e = in_sizes[1] / 2;       // 3200000
    const int* src = ei;
    const int* dst = ei + e;

    // workspace layout
    float* ws   = (float*)d_ws;
    float* h1p  = ws;                               // N*24
    float* h2p  = h1p + (size_t)n * PSTRIDE;        // N*24
    float* g    = h2p + (size_t)n * PSTRIDE;        // 32 (padded)
    int*   deg  = (int*)(g + 32);                   // N
    int*   off  = deg + n;                          // N+1
    int*   cur  = off + n + 1;                      // N
    int*   base = cur + n;                          // 256
    int*   esrc = base + 256;                       // E

    const int B = 256;
    const int nb_n = (n + B - 1) / B;
    const int nb_e = (e + B - 1) / B;
    const int nb_q = (n + (B / 4) - 1) / (B / 4);   // 4 lanes/node
    const int nb_o = (n + (B / 8) - 1) / (B / 8);   // 8 lanes/node

    hipMemsetAsync(deg, 0, (size_t)n * sizeof(int), stream);
    hipMemsetAsync(g, 0, D * sizeof(float), stream);

    k_xw<<<nb_n, B, 0, stream>>>(x, gcn_W, h1p, n);
    k_hist<<<nb_e, B, 0, stream>>>(dst, deg, e);
    k_scan<<<1, 256, 0, stream>>>(deg, base, &off[n], n);
    k_fill<<<256, B, 0, stream>>>(deg, base, off, cur, h1p, n);
    k_scatter<<<nb_e, B, 0, stream>>>(src, dst, cur, esrc, e);
    k_gcn_gat<<<nb_q, B, 0, stream>>>(off, esrc, h1p, gcn_b, gat_W,
                                      att_s, att_d, h2p, n);
    k_gat_agg<<<nb_o, B, 0, stream>>>(off, esrc, h2p, gat_b, g, n);
    k_head<<<1, 64, 0, stream>>>(g, aW1, ab1, aW2, ab2, vW1, vb1, vW2, vb2,
                                 (float*)d_out);
}

// Round 4
// 635.694 us; speedup vs baseline: 4.9440x; 4.9440x over previous
//
#include <hip/hip_runtime.h>

#define D 20
#define ACT 5
#define NEG_SLOPE 0.2f
#define PSTRIDE 24   // packed row stride in floats (96 B, float4-aligned)

__device__ __forceinline__ float leaky(float x) {
    return x > 0.f ? x : NEG_SLOPE * x;
}

// ---------------------------------------------------------------------------
// 1. h1p[i][0..19] = x[i] @ gcn_W   (packed stride-24 rows)
// ---------------------------------------------------------------------------
__global__ void k_xw(const float* __restrict__ x, const float* __restrict__ W,
                     float* __restrict__ h1p, int n) {
    __shared__ float sW[D * D];
    for (int t = threadIdx.x; t < D * D; t += blockDim.x) sW[t] = W[t];
    __syncthreads();
    int i = blockIdx.x * blockDim.x + threadIdx.x;
    if (i >= n) return;
    float xi[D];
    const float4* xr = (const float4*)(x + (size_t)i * D);
#pragma unroll
    for (int q = 0; q < D / 4; ++q) {
        float4 v = xr[q];
        xi[4 * q + 0] = v.x; xi[4 * q + 1] = v.y;
        xi[4 * q + 2] = v.z; xi[4 * q + 3] = v.w;
    }
    float4* hr = (float4*)(h1p + (size_t)i * PSTRIDE);
#pragma unroll
    for (int q = 0; q < D / 4; ++q) {
        float4 o;
        float* op = (float*)&o;
#pragma unroll
        for (int r = 0; r < 4; ++r) {
            int d = 4 * q + r;
            float acc = 0.f;
#pragma unroll
            for (int k = 0; k < D; ++k) acc += xi[k] * sW[k * D + d];
            op[r] = acc;
        }
        hr[q] = o;
    }
}

// ---------------------------------------------------------------------------
// 2. histogram of dst (real in-degree)
// ---------------------------------------------------------------------------
__global__ void k_hist(const int* __restrict__ dst, int* __restrict__ deg, int e) {
    int i = blockIdx.x * blockDim.x + threadIdx.x;
    if (i < e) atomicAdd(&deg[dst[i]], 1);
}

// ---------------------------------------------------------------------------
// 3. single-block: per-chunk partial sums -> base[256]; off[n] = total
// ---------------------------------------------------------------------------
__global__ void k_scan(const int* __restrict__ deg, int* __restrict__ base,
                       int* __restrict__ off_n, int n) {
    __shared__ int ssum[256];
    int t = threadIdx.x;
    int chunk = (n + 255) / 256;
    int lo = t * chunk, hi = min(lo + chunk, n);
    int s = 0;
    for (int i = lo; i < hi; ++i) s += deg[i];
    ssum[t] = s;
    __syncthreads();
    if (t == 0) {
        int run = 0;
        for (int k = 0; k < 256; ++k) { int v = ssum[k]; base[k] = run; run += v; }
        *off_n = run;
    }
}

// ---------------------------------------------------------------------------
// 4. per-chunk fill: off/cur + dinv packed into h1p[.][20]
// ---------------------------------------------------------------------------
__global__ void k_fill(const int* __restrict__ deg, const int* __restrict__ base,
                       int* __restrict__ off, int* __restrict__ cur,
                       float* __restrict__ h1p, int n) {
    __shared__ int sdeg[512];
    int b = blockIdx.x;
    int chunk = (n + 255) / 256;
    int lo = b * chunk, hi = min(lo + chunk, n);
    int len = hi - lo;
    for (int i = threadIdx.x; i < len; i += blockDim.x) {
        int dv = deg[lo + i];
        sdeg[i] = dv;
        h1p[(size_t)(lo + i) * PSTRIDE + 20] = rsqrtf((float)(dv + 1));
    }
    __syncthreads();
    if (threadIdx.x == 0) {
        int run = base[b];
        for (int i = 0; i < len; ++i) { int v = sdeg[i]; sdeg[i] = run; run += v; }
    }
    __syncthreads();
    for (int i = threadIdx.x; i < len; i += blockDim.x) {
        int o = sdeg[i];
        off[lo + i] = o;
        cur[lo + i] = o;
    }
}

// ---------------------------------------------------------------------------
// 5. scatter edges into CSR-by-dst (order within segment irrelevant)
// ---------------------------------------------------------------------------
__global__ void k_scatter(const int* __restrict__ src, const int* __restrict__ dst,
                          int* __restrict__ cur, int* __restrict__ esrc, int e) {
    int i = blockIdx.x * blockDim.x + threadIdx.x;
    if (i >= e) return;
    int p = atomicAdd(&cur[dst[i]], 1);
    esrc[p] = src[i];
}

// ---------------------------------------------------------------------------
// 6. fused GCN gather + relu + GAT node transform. 4 lanes per node.
//    reads h1p (row+dinv packed), writes h2p (row + a_s + a_d packed)
// ---------------------------------------------------------------------------
__global__ void k_gcn_gat(const int* __restrict__ off, const int* __restrict__ esrc,
                          const float* __restrict__ h1p, const float* __restrict__ gcn_b,
                          const float* __restrict__ gat_W, const float* __restrict__ att_s,
                          const float* __restrict__ att_d, float* __restrict__ h2p, int n) {
    __shared__ float sW[D * D], sb[D], sas[D], sad[D];
    for (int t = threadIdx.x; t < D * D; t += blockDim.x) sW[t] = gat_W[t];
    if (threadIdx.x < D) {
        sb[threadIdx.x]  = gcn_b[threadIdx.x];
        sas[threadIdx.x] = att_s[threadIdx.x];
        sad[threadIdx.x] = att_d[threadIdx.x];
    }
    __syncthreads();
    int t = threadIdx.x;
    int i = blockIdx.x * (blockDim.x >> 2) + (t >> 2);
    int q = t & 3;
    bool valid = i < n;

    float acc[D];
#pragma unroll
    for (int d = 0; d < D; ++d) acc[d] = 0.f;
    float di = 0.f;
    if (valid) {
        const float* row = h1p + (size_t)i * PSTRIDE;
        di = row[20];
        if (q == 0) {                       // self-loop term
            float c = di * di;
            const float4* hr = (const float4*)row;
#pragma unroll
            for (int qq = 0; qq < D / 4; ++qq) {
                float4 v = hr[qq];
                acc[4 * qq + 0] = c * v.x; acc[4 * qq + 1] = c * v.y;
                acc[4 * qq + 2] = c * v.z; acc[4 * qq + 3] = c * v.w;
            }
        }
        int s0 = off[i], s1 = off[i + 1];
        for (int j = s0 + q; j < s1; j += 4) {
            int s = esrc[j];
            const float* rs = h1p + (size_t)s * PSTRIDE;
            float norm = di * rs[20];
            const float4* hs = (const float4*)rs;
#pragma unroll
            for (int qq = 0; qq < D / 4; ++qq) {
                float4 v = hs[qq];
                acc[4 * qq + 0] += norm * v.x; acc[4 * qq + 1] += norm * v.y;
                acc[4 * qq + 2] += norm * v.z; acc[4 * qq + 3] += norm * v.w;
            }
        }
    }
    // quad all-reduce of acc
#pragma unroll
    for (int d = 0; d < D; ++d) acc[d] += __shfl_xor(acc[d], 1);
#pragma unroll
    for (int d = 0; d < D; ++d) acc[d] += __shfl_xor(acc[d], 2);

    float v[D];
#pragma unroll
    for (int k = 0; k < D; ++k) {
        float tv = acc[k] + sb[k];
        v[k] = tv > 0.f ? tv : 0.f;
    }
    // each lane computes 5 output channels d = q*5 + r
    float o5[5];
    float as_ = 0.f, ad_ = 0.f;
#pragma unroll
    for (int r = 0; r < 5; ++r) {
        int d = q * 5 + r;
        float a = 0.f;
#pragma unroll
        for (int k = 0; k < D; ++k) a += v[k] * sW[k * D + d];
        o5[r] = a;
        as_ += a * sas[d];
        ad_ += a * sad[d];
    }
    if (valid) {
        float* orow = h2p + (size_t)i * PSTRIDE + q * 5;
#pragma unroll
        for (int r = 0; r < 5; ++r) orow[r] = o5[r];
    }
    as_ += __shfl_xor(as_, 1); as_ += __shfl_xor(as_, 2);
    ad_ += __shfl_xor(ad_, 1); ad_ += __shfl_xor(ad_, 2);
    if (valid && q == 0) {
        h2p[(size_t)i * PSTRIDE + 20] = as_;
        h2p[(size_t)i * PSTRIDE + 21] = ad_;
    }
}

// ---------------------------------------------------------------------------
// 7. GAT online-softmax aggregate, 8 lanes per node; per-block LDS reduce,
//    NO contended atomics: block partial -> partials[d*PB + block]
// ---------------------------------------------------------------------------
__global__ void k_gat_agg(const int* __restrict__ off, const int* __restrict__ esrc,
                          const float* __restrict__ h2p, const float* __restrict__ gat_b,
                          float* __restrict__ partials, int PB, int n) {
    __shared__ float sb[D];
    __shared__ float swave[4][D];
    if (threadIdx.x < D) sb[threadIdx.x] = gat_b[threadIdx.x];
    __syncthreads();
    int t = threadIdx.x;
    int i = blockIdx.x * (blockDim.x >> 3) + (t >> 3);
    int o = t & 7;
    bool valid = i < n;

    float m = -1e30f, den = 0.f;
    float acc[D];
#pragma unroll
    for (int d = 0; d < D; ++d) acc[d] = 0.f;

    if (valid) {
        const float* row = h2p + (size_t)i * PSTRIDE;
        float ad_i = row[21];
        if (o == 0) {                      // self edge seeds the online softmax
            m = leaky(row[20] + ad_i);
            den = 1.f;
            const float4* hr = (const float4*)row;
#pragma unroll
            for (int qq = 0; qq < D / 4; ++qq) {
                float4 v = hr[qq];
                acc[4 * qq + 0] = v.x; acc[4 * qq + 1] = v.y;
                acc[4 * qq + 2] = v.z; acc[4 * qq + 3] = v.w;
            }
        }
        int s0 = off[i], s1 = off[i + 1];
        for (int j = s0 + o; j < s1; j += 8) {
            int s = esrc[j];
            const float* rs = h2p + (size_t)s * PSTRIDE;
            float eg = leaky(rs[20] + ad_i);
            float nm = fmaxf(m, eg);
            float c = __expf(m - nm), w = __expf(eg - nm);
            den = den * c + w;
            const float4* hs = (const float4*)rs;
#pragma unroll
            for (int qq = 0; qq < D / 4; ++qq) {
                float4 v = hs[qq];
                acc[4 * qq + 0] = acc[4 * qq + 0] * c + w * v.x;
                acc[4 * qq + 1] = acc[4 * qq + 1] * c + w * v.y;
                acc[4 * qq + 2] = acc[4 * qq + 2] * c + w * v.z;
                acc[4 * qq + 3] = acc[4 * qq + 3] * c + w * v.w;
            }
            m = nm;
        }
    }
    // octet merge of (m, den, acc)
#pragma unroll
    for (int mask = 1; mask < 8; mask <<= 1) {
        float om = __shfl_xor(m, mask);
        float oden = __shfl_xor(den, mask);
        float nm = fmaxf(m, om);
        float c1 = __expf(m - nm), c2 = __expf(om - nm);
        den = den * c1 + oden * c2;
#pragma unroll
        for (int d = 0; d < D; ++d) {
            float oa = __shfl_xor(acc[d], mask);
            acc[d] = acc[d] * c1 + oa * c2;
        }
        m = nm;
    }
    float inv = den > 0.f ? 1.0f / den : 0.f;
#pragma unroll
    for (int d = 0; d < D; ++d) {
        float vv = acc[d] * inv + sb[d];
        vv = vv > 0.f ? vv : 0.f;
        if (!valid || o != 0) vv = 0.f;    // one contribution per node
        acc[d] = vv;
    }
    // wave reduce each channel -> LDS; 20 threads fold 4 waves -> one
    // uncontended global write per channel per block.
    int wv = t >> 6, ln = t & 63;
#pragma unroll
    for (int d = 0; d < D; ++d) {
        float vv = acc[d];
        for (int s2 = 32; s2; s2 >>= 1) vv += __shfl_down(vv, s2);
        if (ln == 0) swave[wv][d] = vv;
    }
    __syncthreads();
    if (t < D) {
        float s = swave[0][t] + swave[1][t] + swave[2][t] + swave[3][t];
        partials[(size_t)t * PB + blockIdx.x] = s;
    }
}

// ---------------------------------------------------------------------------
// 8. final readout reduce: one block per channel, no atomics
// ---------------------------------------------------------------------------
__global__ void k_reduce(const float* __restrict__ partials, int PB, int nblk,
                         float* __restrict__ g) {
    __shared__ float swave[4];
    int d = blockIdx.x;
    int t = threadIdx.x;
    const float* p = partials + (size_t)d * PB;
    float s = 0.f;
    for (int i = t; i < nblk; i += blockDim.x) s += p[i];
    for (int s2 = 32; s2; s2 >>= 1) s += __shfl_down(s, s2);
    if ((t & 63) == 0) swave[t >> 6] = s;
    __syncthreads();
    if (t == 0) g[d] = swave[0] + swave[1] + swave[2] + swave[3];
}

// ---------------------------------------------------------------------------
// 9. dueling head
// ---------------------------------------------------------------------------
__global__ void k_head(const float* __restrict__ g,
                       const float* __restrict__ aW1, const float* __restrict__ ab1,
                       const float* __restrict__ aW2, const float* __restrict__ ab2,
                       const float* __restrict__ vW1, const float* __restrict__ vb1,
                       const float* __restrict__ vW2, const float* __restrict__ vb2,
                       float* __restrict__ out) {
    __shared__ float sg[D], t1[D], t2[D], A[ACT], V, meanA;
    int t = threadIdx.x;
    if (t < D) sg[t] = g[t];
    __syncthreads();
    if (t < D) {
        float a = ab1[t], v = vb1[t];
        for (int k = 0; k < D; ++k) {
            a += sg[k] * aW1[k * D + t];
            v += sg[k] * vW1[k * D + t];
        }
        t1[t] = a > 0.f ? a : 0.f;
        t2[t] = v > 0.f ? v : 0.f;
    }
    __syncthreads();
    if (t < ACT) {
        float a = ab2[t];
        for (int d = 0; d < D; ++d) a += t1[d] * aW2[d * ACT + t];
        A[t] = a;
    }
    if (t == D) {
        float v = vb2[0];
        for (int d = 0; d < D; ++d) v += t2[d] * vW2[d];
        V = v;
    }
    __syncthreads();
    if (t == 0) {
        float s = 0.f;
        for (int j = 0; j < ACT; ++j) s += A[j];
        meanA = s / ACT;
    }
    __syncthreads();
    if (t < ACT) out[t] = V + A[t] - meanA;
}

extern "C" void kernel_launch(void* const* d_in, const int* in_sizes, int n_in,
                              void* d_out, int out_size, void* d_ws, size_t ws_size,
                              hipStream_t stream) {
    const float* x      = (const float*)d_in[0];
    const int*   ei     = (const int*)d_in[1];
    // d_in[2] edge_attr: unused by the reference
    const float* gcn_W  = (const float*)d_in[3];
    const float* gcn_b  = (const float*)d_in[4];
    const float* gat_W  = (const float*)d_in[5];
    const float* att_s  = (const float*)d_in[6];
    const float* att_d  = (const float*)d_in[7];
    const float* gat_b  = (const float*)d_in[8];
    const float* aW1    = (const float*)d_in[9];
    const float* ab1    = (const float*)d_in[10];
    const float* aW2    = (const float*)d_in[11];
    const float* ab2    = (const float*)d_in[12];
    const float* vW1    = (const float*)d_in[13];
    const float* vb1    = (const float*)d_in[14];
    const float* vW2    = (const float*)d_in[15];
    const float* vb2    = (const float*)d_in[16];

    const int n = in_sizes[0] / D;       // 100000
    const int e = in_sizes[1] / 2;       // 3200000
    const int* src = ei;
    const int* dst = ei + e;

    const int B = 256;
    const int nb_n = (n + B - 1) / B;
    const int nb_e = (e + B - 1) / B;
    const int nb_q = (n + (B / 4) - 1) / (B / 4);   // 4 lanes/node
    const int nb_o = (n + (B / 8) - 1) / (B / 8);   // 8 lanes/node
    const int PB   = (nb_o + 63) & ~63;             // padded partials stride

    // workspace layout
    float* ws       = (float*)d_ws;
    float* h1p      = ws;                               // N*24
    float* h2p      = h1p + (size_t)n * PSTRIDE;        // N*24
    float* g        = h2p + (size_t)n * PSTRIDE;        // 32 (padded)
    float* partials = g + 32;                           // 20*PB
    int*   deg      = (int*)(partials + (size_t)D * PB); // N
    int*   off      = deg + n;                          // N+1
    int*   cur      = off + n + 1;                      // N
    int*   base     = cur + n;                          // 256
    int*   esrc     = base + 256;                       // E

    hipMemsetAsync(deg, 0, (size_t)n * sizeof(int), stream);

    k_xw<<<nb_n, B, 0, stream>>>(x, gcn_W, h1p, n);
    k_hist<<<nb_e, B, 0, stream>>>(dst, deg, e);
    k_scan<<<1, 256, 0, stream>>>(deg, base, &off[n], n);
    k_fill<<<256, B, 0, stream>>>(deg, base, off, cur, h1p, n);
    k_scatter<<<nb_e, B, 0, stream>>>(src, dst, cur, esrc, e);
    k_gcn_gat<<<nb_q, B, 0, stream>>>(off, esrc, h1p, gcn_b, gat_W,
                                      att_s, att_d, h2p, n);
    k_gat_agg<<<nb_o, B, 0, stream>>>(off, esrc, h2p, gat_b, partials, PB, n);
    k_reduce<<<D, B, 0, stream>>>(partials, PB, nb_o, g);
    k_head<<<1, 64, 0, stream>>>(g, aW1, ab1, aW2, ab2, vW1, vb1, vW2, vb2,
                                 (float*)d_out);
}

// Round 5
// 470.485 us; speedup vs baseline: 6.6800x; 1.3511x over previous
//
#include <hip/hip_runtime.h>

#define D 20
#define ACT 5
#define NEG_SLOPE 0.2f
#define PSTRIDE 24   // packed row stride in floats (96 B, float4-aligned)
#define NBUK 512     // dst buckets of 256 nodes (dst >> 8)

__device__ __forceinline__ float leaky(float x) {
    return x > 0.f ? x : NEG_SLOPE * x;
}

// ---------------------------------------------------------------------------
// 1. histogram of dst (real in-degree)
// ---------------------------------------------------------------------------
__global__ void k_hist(const int* __restrict__ dst, int* __restrict__ deg, int e) {
    int i = blockIdx.x * blockDim.x + threadIdx.x;
    if (i < e) atomicAdd(&deg[dst[i]], 1);
}

// ---------------------------------------------------------------------------
// 2. single-block: per-chunk partial sums -> base[256]; off[n] = total
// ---------------------------------------------------------------------------
__global__ void k_scan(const int* __restrict__ deg, int* __restrict__ base,
                       int* __restrict__ off_n, int n) {
    __shared__ int ssum[256];
    int t = threadIdx.x;
    int chunk = (n + 255) / 256;
    int lo = t * chunk, hi = min(lo + chunk, n);
    int s = 0;
    for (int i = lo; i < hi; ++i) s += deg[i];
    ssum[t] = s;
    __syncthreads();
    if (t == 0) {
        int run = 0;
        for (int k = 0; k < 256; ++k) { int v = ssum[k]; base[k] = run; run += v; }
        *off_n = run;
    }
}

// ---------------------------------------------------------------------------
// 3. per-chunk fill: off, cur
// ---------------------------------------------------------------------------
__global__ void k_fill(const int* __restrict__ deg, const int* __restrict__ base,
                       int* __restrict__ off, int* __restrict__ cur, int n) {
    __shared__ int sdeg[512];
    int b = blockIdx.x;
    int chunk = (n + 255) / 256;
    int lo = b * chunk, hi = min(lo + chunk, n);
    int len = hi - lo;
    for (int i = threadIdx.x; i < len; i += blockDim.x) sdeg[i] = deg[lo + i];
    __syncthreads();
    if (threadIdx.x == 0) {
        int run = base[b];
        for (int i = 0; i < len; ++i) { int v = sdeg[i]; sdeg[i] = run; run += v; }
    }
    __syncthreads();
    for (int i = threadIdx.x; i < len; i += blockDim.x) {
        int o = sdeg[i];
        off[lo + i] = o;
        cur[lo + i] = o;
    }
}

// ---------------------------------------------------------------------------
// 4. bucket cursors: bcur[b] = off[min(b<<8, n)]
// ---------------------------------------------------------------------------
__global__ void k_binit(const int* __restrict__ off, int* __restrict__ bcur, int n) {
    int b = threadIdx.x;
    if (b < NBUK) bcur[b] = off[min(b << 8, n)];
}

// ---------------------------------------------------------------------------
// 5. bin edges by dst bucket into tmp (packed src<<8 | dst&255).
//    LDS histogram + per-block reservation -> semi-coalesced writes.
// ---------------------------------------------------------------------------
__global__ void k_bin(const int* __restrict__ src, const int* __restrict__ dst,
                      int* __restrict__ bcur, unsigned* __restrict__ tmp,
                      int e, int nba) {
    __shared__ int lh[NBUK];
    for (int b = threadIdx.x; b < NBUK; b += blockDim.x) lh[b] = 0;
    __syncthreads();
    int chunk = (e + nba - 1) / nba;
    int lo = blockIdx.x * chunk, hi = min(lo + chunk, e);
    for (int j = lo + threadIdx.x; j < hi; j += blockDim.x)
        atomicAdd(&lh[dst[j] >> 8], 1);
    __syncthreads();
    for (int b = threadIdx.x; b < NBUK; b += blockDim.x) {
        int c = lh[b];
        lh[b] = c ? atomicAdd(&bcur[b], c) : 0;
    }
    __syncthreads();
    for (int j = lo + threadIdx.x; j < hi; j += blockDim.x) {
        int t = dst[j];
        int p = atomicAdd(&lh[t >> 8], 1);
        tmp[p] = ((unsigned)src[j] << 8) | (unsigned)(t & 255);
    }
}

// ---------------------------------------------------------------------------
// 6. final scatter within buckets: cur/esrc windows are L2-hot
// ---------------------------------------------------------------------------
__global__ void k_scatter2(const unsigned* __restrict__ tmp, const int* __restrict__ off,
                           int* __restrict__ cur, int* __restrict__ esrc, int n) {
    int b = blockIdx.x;
    int lo = off[min(b << 8, n)];
    int hi = off[min((b + 1) << 8, n)];
    for (int i = lo + threadIdx.x; i < hi; i += blockDim.x) {
        unsigned v = tmp[i];
        int t = (b << 8) | (int)(v & 255u);
        int p = atomicAdd(&cur[t], 1);
        esrc[p] = (int)(v >> 8);
    }
}

// ---------------------------------------------------------------------------
// 7. h1p[i][0..19] = x[i] @ gcn_W ; h1p[i][20] = dinv (from off diffs)
//    (runs AFTER scatter: h1p region aliases tmp)
// ---------------------------------------------------------------------------
__global__ void k_xw(const float* __restrict__ x, const float* __restrict__ W,
                     const int* __restrict__ off, float* __restrict__ h1p, int n) {
    __shared__ float sW[D * D];
    for (int t = threadIdx.x; t < D * D; t += blockDim.x) sW[t] = W[t];
    __syncthreads();
    int i = blockIdx.x * blockDim.x + threadIdx.x;
    if (i >= n) return;
    float xi[D];
    const float4* xr = (const float4*)(x + (size_t)i * D);
#pragma unroll
    for (int q = 0; q < D / 4; ++q) {
        float4 v = xr[q];
        xi[4 * q + 0] = v.x; xi[4 * q + 1] = v.y;
        xi[4 * q + 2] = v.z; xi[4 * q + 3] = v.w;
    }
    float4* hr = (float4*)(h1p + (size_t)i * PSTRIDE);
#pragma unroll
    for (int q = 0; q < D / 4; ++q) {
        float4 o;
        float* op = (float*)&o;
#pragma unroll
        for (int r = 0; r < 4; ++r) {
            int d = 4 * q + r;
            float acc = 0.f;
#pragma unroll
            for (int k = 0; k < D; ++k) acc += xi[k] * sW[k * D + d];
            op[r] = acc;
        }
        hr[q] = o;
    }
    int dg = off[i + 1] - off[i];
    h1p[(size_t)i * PSTRIDE + 20] = rsqrtf((float)(dg + 1));
}

// ---------------------------------------------------------------------------
// 8. fused GCN gather + relu + GAT node transform. 4 lanes per node.
// ---------------------------------------------------------------------------
__global__ void k_gcn_gat(const int* __restrict__ off, const int* __restrict__ esrc,
                          const float* __restrict__ h1p, const float* __restrict__ gcn_b,
                          const float* __restrict__ gat_W, const float* __restrict__ att_s,
                          const float* __restrict__ att_d, float* __restrict__ h2p, int n) {
    __shared__ float sW[D * D], sb[D], sas[D], sad[D];
    for (int t = threadIdx.x; t < D * D; t += blockDim.x) sW[t] = gat_W[t];
    if (threadIdx.x < D) {
        sb[threadIdx.x]  = gcn_b[threadIdx.x];
        sas[threadIdx.x] = att_s[threadIdx.x];
        sad[threadIdx.x] = att_d[threadIdx.x];
    }
    __syncthreads();
    int t = threadIdx.x;
    int i = blockIdx.x * (blockDim.x >> 2) + (t >> 2);
    int q = t & 3;
    bool valid = i < n;

    float acc[D];
#pragma unroll
    for (int d = 0; d < D; ++d) acc[d] = 0.f;
    float di = 0.f;
    if (valid) {
        const float* row = h1p + (size_t)i * PSTRIDE;
        di = row[20];
        if (q == 0) {                       // self-loop term
            float c = di * di;
            const float4* hr = (const float4*)row;
#pragma unroll
            for (int qq = 0; qq < D / 4; ++qq) {
                float4 v = hr[qq];
                acc[4 * qq + 0] = c * v.x; acc[4 * qq + 1] = c * v.y;
                acc[4 * qq + 2] = c * v.z; acc[4 * qq + 3] = c * v.w;
            }
        }
        int s0 = off[i], s1 = off[i + 1];
        for (int j = s0 + q; j < s1; j += 4) {
            int s = esrc[j];
            const float* rs = h1p + (size_t)s * PSTRIDE;
            float norm = di * rs[20];
            const float4* hs = (const float4*)rs;
#pragma unroll
            for (int qq = 0; qq < D / 4; ++qq) {
                float4 v = hs[qq];
                acc[4 * qq + 0] += norm * v.x; acc[4 * qq + 1] += norm * v.y;
                acc[4 * qq + 2] += norm * v.z; acc[4 * qq + 3] += norm * v.w;
            }
        }
    }
    // quad all-reduce of acc
#pragma unroll
    for (int d = 0; d < D; ++d) acc[d] += __shfl_xor(acc[d], 1);
#pragma unroll
    for (int d = 0; d < D; ++d) acc[d] += __shfl_xor(acc[d], 2);

    float v[D];
#pragma unroll
    for (int k = 0; k < D; ++k) {
        float tv = acc[k] + sb[k];
        v[k] = tv > 0.f ? tv : 0.f;
    }
    float o5[5];
    float as_ = 0.f, ad_ = 0.f;
#pragma unroll
    for (int r = 0; r < 5; ++r) {
        int d = q * 5 + r;
        float a = 0.f;
#pragma unroll
        for (int k = 0; k < D; ++k) a += v[k] * sW[k * D + d];
        o5[r] = a;
        as_ += a * sas[d];
        ad_ += a * sad[d];
    }
    if (valid) {
        float* orow = h2p + (size_t)i * PSTRIDE + q * 5;
#pragma unroll
        for (int r = 0; r < 5; ++r) orow[r] = o5[r];
    }
    as_ += __shfl_xor(as_, 1); as_ += __shfl_xor(as_, 2);
    ad_ += __shfl_xor(ad_, 1); ad_ += __shfl_xor(ad_, 2);
    if (valid && q == 0) {
        h2p[(size_t)i * PSTRIDE + 20] = as_;
        h2p[(size_t)i * PSTRIDE + 21] = ad_;
    }
}

// ---------------------------------------------------------------------------
// 9. GAT online-softmax aggregate, 8 lanes per node; block partial to
//    partials[d*PB + block] (no contended atomics)
// ---------------------------------------------------------------------------
__global__ void k_gat_agg(const int* __restrict__ off, const int* __restrict__ esrc,
                          const float* __restrict__ h2p, const float* __restrict__ gat_b,
                          float* __restrict__ partials, int PB, int n) {
    __shared__ float sb[D];
    __shared__ float swave[4][D];
    if (threadIdx.x < D) sb[threadIdx.x] = gat_b[threadIdx.x];
    __syncthreads();
    int t = threadIdx.x;
    int i = blockIdx.x * (blockDim.x >> 3) + (t >> 3);
    int o = t & 7;
    bool valid = i < n;

    float m = -1e30f, den = 0.f;
    float acc[D];
#pragma unroll
    for (int d = 0; d < D; ++d) acc[d] = 0.f;

    if (valid) {
        const float* row = h2p + (size_t)i * PSTRIDE;
        float ad_i = row[21];
        if (o == 0) {                      // self edge seeds the online softmax
            m = leaky(row[20] + ad_i);
            den = 1.f;
            const float4* hr = (const float4*)row;
#pragma unroll
            for (int qq = 0; qq < D / 4; ++qq) {
                float4 v = hr[qq];
                acc[4 * qq + 0] = v.x; acc[4 * qq + 1] = v.y;
                acc[4 * qq + 2] = v.z; acc[4 * qq + 3] = v.w;
            }
        }
        int s0 = off[i], s1 = off[i + 1];
        for (int j = s0 + o; j < s1; j += 8) {
            int s = esrc[j];
            const float* rs = h2p + (size_t)s * PSTRIDE;
            float eg = leaky(rs[20] + ad_i);
            float nm = fmaxf(m, eg);
            float c = __expf(m - nm), w = __expf(eg - nm);
            den = den * c + w;
            const float4* hs = (const float4*)rs;
#pragma unroll
            for (int qq = 0; qq < D / 4; ++qq) {
                float4 v = hs[qq];
                acc[4 * qq + 0] = acc[4 * qq + 0] * c + w * v.x;
                acc[4 * qq + 1] = acc[4 * qq + 1] * c + w * v.y;
                acc[4 * qq + 2] = acc[4 * qq + 2] * c + w * v.z;
                acc[4 * qq + 3] = acc[4 * qq + 3] * c + w * v.w;
            }
            m = nm;
        }
    }
    // octet merge of (m, den, acc)
#pragma unroll
    for (int mask = 1; mask < 8; mask <<= 1) {
        float om = __shfl_xor(m, mask);
        float oden = __shfl_xor(den, mask);
        float nm = fmaxf(m, om);
        float c1 = __expf(m - nm), c2 = __expf(om - nm);
        den = den * c1 + oden * c2;
#pragma unroll
        for (int d = 0; d < D; ++d) {
            float oa = __shfl_xor(acc[d], mask);
            acc[d] = acc[d] * c1 + oa * c2;
        }
        m = nm;
    }
    float inv = den > 0.f ? 1.0f / den : 0.f;
#pragma unroll
    for (int d = 0; d < D; ++d) {
        float vv = acc[d] * inv + sb[d];
        vv = vv > 0.f ? vv : 0.f;
        if (!valid || o != 0) vv = 0.f;    // one contribution per node
        acc[d] = vv;
    }
    int wv = t >> 6, ln = t & 63;
#pragma unroll
    for (int d = 0; d < D; ++d) {
        float vv = acc[d];
        for (int s2 = 32; s2; s2 >>= 1) vv += __shfl_down(vv, s2);
        if (ln == 0) swave[wv][d] = vv;
    }
    __syncthreads();
    if (t < D) {
        float s = swave[0][t] + swave[1][t] + swave[2][t] + swave[3][t];
        partials[(size_t)t * PB + blockIdx.x] = s;
    }
}

// ---------------------------------------------------------------------------
// 10. final readout reduce: one block per channel, no atomics
// ---------------------------------------------------------------------------
__global__ void k_reduce(const float* __restrict__ partials, int PB, int nblk,
                         float* __restrict__ g) {
    __shared__ float swave[4];
    int d = blockIdx.x;
    int t = threadIdx.x;
    const float* p = partials + (size_t)d * PB;
    float s = 0.f;
    for (int i = t; i < nblk; i += blockDim.x) s += p[i];
    for (int s2 = 32; s2; s2 >>= 1) s += __shfl_down(s, s2);
    if ((t & 63) == 0) swave[t >> 6] = s;
    __syncthreads();
    if (t == 0) g[d] = swave[0] + swave[1] + swave[2] + swave[3];
}

// ---------------------------------------------------------------------------
// 11. dueling head
// ---------------------------------------------------------------------------
__global__ void k_head(const float* __restrict__ g,
                       const float* __restrict__ aW1, const float* __restrict__ ab1,
                       const float* __restrict__ aW2, const float* __restrict__ ab2,
                       const float* __restrict__ vW1, const float* __restrict__ vb1,
                       const float* __restrict__ vW2, const float* __restrict__ vb2,
                       float* __restrict__ out) {
    __shared__ float sg[D], t1[D], t2[D], A[ACT], V, meanA;
    int t = threadIdx.x;
    if (t < D) sg[t] = g[t];
    __syncthreads();
    if (t < D) {
        float a = ab1[t], v = vb1[t];
        for (int k = 0; k < D; ++k) {
            a += sg[k] * aW1[k * D + t];
            v += sg[k] * vW1[k * D + t];
        }
        t1[t] = a > 0.f ? a : 0.f;
        t2[t] = v > 0.f ? v : 0.f;
    }
    __syncthreads();
    if (t < ACT) {
        float a = ab2[t];
        for (int d = 0; d < D; ++d) a += t1[d] * aW2[d * ACT + t];
        A[t] = a;
    }
    if (t == D) {
        float v = vb2[0];
        for (int d = 0; d < D; ++d) v += t2[d] * vW2[d];
        V = v;
    }
    __syncthreads();
    if (t == 0) {
        float s = 0.f;
        for (int j = 0; j < ACT; ++j) s += A[j];
        meanA = s / ACT;
    }
    __syncthreads();
    if (t < ACT) out[t] = V + A[t] - meanA;
}

extern "C" void kernel_launch(void* const* d_in, const int* in_sizes, int n_in,
                              void* d_out, int out_size, void* d_ws, size_t ws_size,
                              hipStream_t stream) {
    const float* x      = (const float*)d_in[0];
    const int*   ei     = (const int*)d_in[1];
    // d_in[2] edge_attr: unused by the reference
    const float* gcn_W  = (const float*)d_in[3];
    const float* gcn_b  = (const float*)d_in[4];
    const float* gat_W  = (const float*)d_in[5];
    const float* att_s  = (const float*)d_in[6];
    const float* att_d  = (const float*)d_in[7];
    const float* gat_b  = (const float*)d_in[8];
    const float* aW1    = (const float*)d_in[9];
    const float* ab1    = (const float*)d_in[10];
    const float* aW2    = (const float*)d_in[11];
    const float* ab2    = (const float*)d_in[12];
    const float* vW1    = (const float*)d_in[13];
    const float* vb1    = (const float*)d_in[14];
    const float* vW2    = (const float*)d_in[15];
    const float* vb2    = (const float*)d_in[16];

    const int n = in_sizes[0] / D;       // 100000
    const int e = in_sizes[1] / 2;       // 3200000
    const int* src = ei;
    const int* dst = ei + e;

    const int B = 256;
    const int nb_n = (n + B - 1) / B;
    const int nb_e = (e + B - 1) / B;
    const int nb_q = (n + (B / 4) - 1) / (B / 4);   // 4 lanes/node
    const int nb_o = (n + (B / 8) - 1) / (B / 8);   // 8 lanes/node
    const int PB   = (nb_o + 63) & ~63;             // padded partials stride
    const int NBA  = 256;                           // binning blocks
    const int nbuk_used = (n + 255) >> 8;           // 391

    // workspace layout
    float* ws       = (float*)d_ws;
    float* h1p      = ws;                               // N*24
    float* h2p      = h1p + (size_t)n * PSTRIDE;        // N*24
    float* g        = h2p + (size_t)n * PSTRIDE;        // 32 (padded)
    float* partials = g + 32;                           // D*PB
    int*   deg      = (int*)(partials + (size_t)D * PB); // N
    int*   off      = deg + n;                          // N+1
    int*   cur      = off + n + 1;                      // N
    int*   base     = cur + n;                          // 256
    int*   bcur     = base + 256;                       // NBUK
    int*   esrc     = bcur + NBUK;                      // E
    unsigned* tmp   = (unsigned*)h1p;                   // E (aliases h1p+h2p head;
                                                        //    dead before k_xw runs)

    hipMemsetAsync(deg, 0, (size_t)n * sizeof(int), stream);

    k_hist<<<nb_e, B, 0, stream>>>(dst, deg, e);
    k_scan<<<1, 256, 0, stream>>>(deg, base, &off[n], n);
    k_fill<<<256, B, 0, stream>>>(deg, base, off, cur, n);
    k_binit<<<1, NBUK, 0, stream>>>(off, bcur, n);
    k_bin<<<NBA, B, 0, stream>>>(src, dst, bcur, tmp, e, NBA);
    k_scatter2<<<nbuk_used, B, 0, stream>>>(tmp, off, cur, esrc, n);
    k_xw<<<nb_n, B, 0, stream>>>(x, gcn_W, off, h1p, n);
    k_gcn_gat<<<nb_q, B, 0, stream>>>(off, esrc, h1p, gcn_b, gat_W,
                                      att_s, att_d, h2p, n);
    k_gat_agg<<<nb_o, B, 0, stream>>>(off, esrc, h2p, gat_b, partials, PB, n);
    k_reduce<<<D, B, 0, stream>>>(partials, PB, nb_o, g);
    k_head<<<1, 64, 0, stream>>>(g, aW1, ab1, aW2, ab2, vW1, vb1, vW2, vb2,
                                 (float*)d_out);
}

// Round 6
// 272.513 us; speedup vs baseline: 11.5329x; 1.7265x over previous
//
#include <hip/hip_runtime.h>

#define D 20
#define ACT 5
#define NEG_SLOPE 0.2f
#define PSTRIDE 24   // packed row stride in floats (96 B, float4-aligned)
#define NBUK 512     // dst buckets of 256 nodes (dst >> 8)

__device__ __forceinline__ float leaky(float x) {
    return x > 0.f ? x : NEG_SLOPE * x;
}

// ---------------------------------------------------------------------------
// 1. bucket histogram of dst (512 buckets, LDS-aggregated, int4 loads)
// ---------------------------------------------------------------------------
__global__ void k_bhist(const int* __restrict__ dst, int* __restrict__ bkt, int e) {
    __shared__ int lh[NBUK];
    for (int b = threadIdx.x; b < NBUK; b += blockDim.x) lh[b] = 0;
    __syncthreads();
    int stride = gridDim.x * blockDim.x;
    int tid = blockIdx.x * blockDim.x + threadIdx.x;
    int n4 = e >> 2;
    const int4* d4 = (const int4*)dst;
    for (int i = tid; i < n4; i += stride) {
        int4 v = d4[i];
        atomicAdd(&lh[v.x >> 8], 1);
        atomicAdd(&lh[v.y >> 8], 1);
        atomicAdd(&lh[v.z >> 8], 1);
        atomicAdd(&lh[v.w >> 8], 1);
    }
    for (int i = (n4 << 2) + tid; i < e; i += stride)
        atomicAdd(&lh[dst[i] >> 8], 1);
    __syncthreads();
    for (int b = threadIdx.x; b < NBUK; b += blockDim.x) {
        int c = lh[b];
        if (c) atomicAdd(&bkt[b], c);
    }
}

// ---------------------------------------------------------------------------
// 2. single-block scan of bucket counts -> bbase[513], bcur; off[n] = e
// ---------------------------------------------------------------------------
__global__ void k_bscan(const int* __restrict__ bkt, int* __restrict__ bbase,
                        int* __restrict__ bcur, int* __restrict__ off_n, int e) {
    if (threadIdx.x == 0) {
        int run = 0;
        for (int k = 0; k < NBUK; ++k) {
            bbase[k] = run; bcur[k] = run; run += bkt[k];
        }
        bbase[NBUK] = run;
        *off_n = e;
    }
}

// ---------------------------------------------------------------------------
// 3. bin edges by dst bucket into tmp (packed src<<8 | dst&255)
// ---------------------------------------------------------------------------
__global__ void k_bin(const int* __restrict__ src, const int* __restrict__ dst,
                      int* __restrict__ bcur, unsigned* __restrict__ tmp,
                      int e, int nba) {
    __shared__ int lh[NBUK];
    for (int b = threadIdx.x; b < NBUK; b += blockDim.x) lh[b] = 0;
    __syncthreads();
    int chunk = (e + nba - 1) / nba;
    int lo = blockIdx.x * chunk, hi = min(lo + chunk, e);
    for (int j = lo + threadIdx.x; j < hi; j += blockDim.x)
        atomicAdd(&lh[dst[j] >> 8], 1);
    __syncthreads();
    for (int b = threadIdx.x; b < NBUK; b += blockDim.x) {
        int c = lh[b];
        lh[b] = c ? atomicAdd(&bcur[b], c) : 0;
    }
    __syncthreads();
    for (int j = lo + threadIdx.x; j < hi; j += blockDim.x) {
        int t = dst[j];
        int p = atomicAdd(&lh[t >> 8], 1);
        tmp[p] = ((unsigned)src[j] << 8) | (unsigned)(t & 255);
    }
}

// ---------------------------------------------------------------------------
// 4. per-bucket: LDS node histogram + block scan -> off[]; LDS-cursor scatter
//    (replaces global deg/cur/k_scan/k_fill entirely)
// ---------------------------------------------------------------------------
__global__ void k_scatter2(const unsigned* __restrict__ tmp, const int* __restrict__ bbase,
                           int* __restrict__ off, int* __restrict__ esrc, int n) {
    __shared__ int ldeg[256];
    __shared__ int lcur[256];
    __shared__ int wtot[4];
    int b = blockIdx.x;
    int t = threadIdx.x;
    int nlo = b << 8;
    int nloc = min(nlo + 256, n) - nlo;       // nodes in this bucket
    int lo = bbase[b], hi = bbase[b + 1];

    ldeg[t] = 0;
    __syncthreads();
    for (int i = lo + t; i < hi; i += blockDim.x)
        atomicAdd(&ldeg[tmp[i] & 255u], 1);
    __syncthreads();

    // exclusive block scan of ldeg
    int v = ldeg[t];
    int lane = t & 63, wv = t >> 6;
    int s = v;
    for (int o = 1; o < 64; o <<= 1) {
        int u = __shfl_up(s, o);
        if (lane >= o) s += u;
    }
    if (lane == 63) wtot[wv] = s;
    __syncthreads();
    int wb = 0;
    for (int k = 0; k < wv; ++k) wb += wtot[k];
    int pos = lo + wb + s - v;                // exclusive prefix + bucket base
    if (t < nloc) off[nlo + t] = pos;
    lcur[t] = pos;
    __syncthreads();

    for (int i = lo + t; i < hi; i += blockDim.x) {
        unsigned w = tmp[i];
        int p = atomicAdd(&lcur[w & 255u], 1);
        esrc[p] = (int)(w >> 8);
    }
}

// ---------------------------------------------------------------------------
// 5. h1p[i][0..19] = x[i] @ gcn_W ; h1p[i][20] = dinv (from off diffs)
//    (runs AFTER scatter: h1p region aliases tmp)
// ---------------------------------------------------------------------------
__global__ void k_xw(const float* __restrict__ x, const float* __restrict__ W,
                     const int* __restrict__ off, float* __restrict__ h1p, int n) {
    __shared__ float sW[D * D];
    for (int t = threadIdx.x; t < D * D; t += blockDim.x) sW[t] = W[t];
    __syncthreads();
    int i = blockIdx.x * blockDim.x + threadIdx.x;
    if (i >= n) return;
    float xi[D];
    const float4* xr = (const float4*)(x + (size_t)i * D);
#pragma unroll
    for (int q = 0; q < D / 4; ++q) {
        float4 v = xr[q];
        xi[4 * q + 0] = v.x; xi[4 * q + 1] = v.y;
        xi[4 * q + 2] = v.z; xi[4 * q + 3] = v.w;
    }
    float4* hr = (float4*)(h1p + (size_t)i * PSTRIDE);
#pragma unroll
    for (int q = 0; q < D / 4; ++q) {
        float4 o;
        float* op = (float*)&o;
#pragma unroll
        for (int r = 0; r < 4; ++r) {
            int d = 4 * q + r;
            float acc = 0.f;
#pragma unroll
            for (int k = 0; k < D; ++k) acc += xi[k] * sW[k * D + d];
            op[r] = acc;
        }
        hr[q] = o;
    }
    int dg = off[i + 1] - off[i];
    h1p[(size_t)i * PSTRIDE + 20] = rsqrtf((float)(dg + 1));
}

// ---------------------------------------------------------------------------
// 6. fused GCN gather + relu + GAT node transform. 4 lanes per node.
// ---------------------------------------------------------------------------
__global__ void k_gcn_gat(const int* __restrict__ off, const int* __restrict__ esrc,
                          const float* __restrict__ h1p, const float* __restrict__ gcn_b,
                          const float* __restrict__ gat_W, const float* __restrict__ att_s,
                          const float* __restrict__ att_d, float* __restrict__ h2p, int n) {
    __shared__ float sW[D * D], sb[D], sas[D], sad[D];
    for (int t = threadIdx.x; t < D * D; t += blockDim.x) sW[t] = gat_W[t];
    if (threadIdx.x < D) {
        sb[threadIdx.x]  = gcn_b[threadIdx.x];
        sas[threadIdx.x] = att_s[threadIdx.x];
        sad[threadIdx.x] = att_d[threadIdx.x];
    }
    __syncthreads();
    int t = threadIdx.x;
    int i = blockIdx.x * (blockDim.x >> 2) + (t >> 2);
    int q = t & 3;
    bool valid = i < n;

    float acc[D];
#pragma unroll
    for (int d = 0; d < D; ++d) acc[d] = 0.f;
    float di = 0.f;
    if (valid) {
        const float* row = h1p + (size_t)i * PSTRIDE;
        di = row[20];
        if (q == 0) {                       // self-loop term
            float c = di * di;
            const float4* hr = (const float4*)row;
#pragma unroll
            for (int qq = 0; qq < D / 4; ++qq) {
                float4 v = hr[qq];
                acc[4 * qq + 0] = c * v.x; acc[4 * qq + 1] = c * v.y;
                acc[4 * qq + 2] = c * v.z; acc[4 * qq + 3] = c * v.w;
            }
        }
        int s0 = off[i], s1 = off[i + 1];
        for (int j = s0 + q; j < s1; j += 4) {
            int s = esrc[j];
            const float* rs = h1p + (size_t)s * PSTRIDE;
            float norm = di * rs[20];
            const float4* hs = (const float4*)rs;
#pragma unroll
            for (int qq = 0; qq < D / 4; ++qq) {
                float4 v = hs[qq];
                acc[4 * qq + 0] += norm * v.x; acc[4 * qq + 1] += norm * v.y;
                acc[4 * qq + 2] += norm * v.z; acc[4 * qq + 3] += norm * v.w;
            }
        }
    }
    // quad all-reduce of acc
#pragma unroll
    for (int d = 0; d < D; ++d) acc[d] += __shfl_xor(acc[d], 1);
#pragma unroll
    for (int d = 0; d < D; ++d) acc[d] += __shfl_xor(acc[d], 2);

    float v[D];
#pragma unroll
    for (int k = 0; k < D; ++k) {
        float tv = acc[k] + sb[k];
        v[k] = tv > 0.f ? tv : 0.f;
    }
    float o5[5];
    float as_ = 0.f, ad_ = 0.f;
#pragma unroll
    for (int r = 0; r < 5; ++r) {
        int d = q * 5 + r;
        float a = 0.f;
#pragma unroll
        for (int k = 0; k < D; ++k) a += v[k] * sW[k * D + d];
        o5[r] = a;
        as_ += a * sas[d];
        ad_ += a * sad[d];
    }
    if (valid) {
        float* orow = h2p + (size_t)i * PSTRIDE + q * 5;
#pragma unroll
        for (int r = 0; r < 5; ++r) orow[r] = o5[r];
    }
    as_ += __shfl_xor(as_, 1); as_ += __shfl_xor(as_, 2);
    ad_ += __shfl_xor(ad_, 1); ad_ += __shfl_xor(ad_, 2);
    if (valid && q == 0) {
        h2p[(size_t)i * PSTRIDE + 20] = as_;
        h2p[(size_t)i * PSTRIDE + 21] = ad_;
    }
}

// ---------------------------------------------------------------------------
// 7. GAT online-softmax aggregate, 8 lanes per node; block partial to
//    partials[d*PB + block] (no contended atomics)
// ---------------------------------------------------------------------------
__global__ void k_gat_agg(const int* __restrict__ off, const int* __restrict__ esrc,
                          const float* __restrict__ h2p, const float* __restrict__ gat_b,
                          float* __restrict__ partials, int PB, int n) {
    __shared__ float sb[D];
    __shared__ float swave[4][D];
    if (threadIdx.x < D) sb[threadIdx.x] = gat_b[threadIdx.x];
    __syncthreads();
    int t = threadIdx.x;
    int i = blockIdx.x * (blockDim.x >> 3) + (t >> 3);
    int o = t & 7;
    bool valid = i < n;

    float m = -1e30f, den = 0.f;
    float acc[D];
#pragma unroll
    for (int d = 0; d < D; ++d) acc[d] = 0.f;

    if (valid) {
        const float* row = h2p + (size_t)i * PSTRIDE;
        float ad_i = row[21];
        if (o == 0) {                      // self edge seeds the online softmax
            m = leaky(row[20] + ad_i);
            den = 1.f;
            const float4* hr = (const float4*)row;
#pragma unroll
            for (int qq = 0; qq < D / 4; ++qq) {
                float4 v = hr[qq];
                acc[4 * qq + 0] = v.x; acc[4 * qq + 1] = v.y;
                acc[4 * qq + 2] = v.z; acc[4 * qq + 3] = v.w;
            }
        }
        int s0 = off[i], s1 = off[i + 1];
        for (int j = s0 + o; j < s1; j += 8) {
            int s = esrc[j];
            const float* rs = h2p + (size_t)s * PSTRIDE;
            float eg = leaky(rs[20] + ad_i);
            float nm = fmaxf(m, eg);
            float c = __expf(m - nm), w = __expf(eg - nm);
            den = den * c + w;
            const float4* hs = (const float4*)rs;
#pragma unroll
            for (int qq = 0; qq < D / 4; ++qq) {
                float4 v = hs[qq];
                acc[4 * qq + 0] = acc[4 * qq + 0] * c + w * v.x;
                acc[4 * qq + 1] = acc[4 * qq + 1] * c + w * v.y;
                acc[4 * qq + 2] = acc[4 * qq + 2] * c + w * v.z;
                acc[4 * qq + 3] = acc[4 * qq + 3] * c + w * v.w;
            }
            m = nm;
        }
    }
    // octet merge of (m, den, acc)
#pragma unroll
    for (int mask = 1; mask < 8; mask <<= 1) {
        float om = __shfl_xor(m, mask);
        float oden = __shfl_xor(den, mask);
        float nm = fmaxf(m, om);
        float c1 = __expf(m - nm), c2 = __expf(om - nm);
        den = den * c1 + oden * c2;
#pragma unroll
        for (int d = 0; d < D; ++d) {
            float oa = __shfl_xor(acc[d], mask);
            acc[d] = acc[d] * c1 + oa * c2;
        }
        m = nm;
    }
    float inv = den > 0.f ? 1.0f / den : 0.f;
#pragma unroll
    for (int d = 0; d < D; ++d) {
        float vv = acc[d] * inv + sb[d];
        vv = vv > 0.f ? vv : 0.f;
        if (!valid || o != 0) vv = 0.f;    // one contribution per node
        acc[d] = vv;
    }
    int wv = t >> 6, ln = t & 63;
#pragma unroll
    for (int d = 0; d < D; ++d) {
        float vv = acc[d];
        for (int s2 = 32; s2; s2 >>= 1) vv += __shfl_down(vv, s2);
        if (ln == 0) swave[wv][d] = vv;
    }
    __syncthreads();
    if (t < D) {
        float s = swave[0][t] + swave[1][t] + swave[2][t] + swave[3][t];
        partials[(size_t)t * PB + blockIdx.x] = s;
    }
}

// ---------------------------------------------------------------------------
// 8. final readout reduce: one block per channel, no atomics
// ---------------------------------------------------------------------------
__global__ void k_reduce(const float* __restrict__ partials, int PB, int nblk,
                         float* __restrict__ g) {
    __shared__ float swave[4];
    int d = blockIdx.x;
    int t = threadIdx.x;
    const float* p = partials + (size_t)d * PB;
    float s = 0.f;
    for (int i = t; i < nblk; i += blockDim.x) s += p[i];
    for (int s2 = 32; s2; s2 >>= 1) s += __shfl_down(s, s2);
    if ((t & 63) == 0) swave[t >> 6] = s;
    __syncthreads();
    if (t == 0) g[d] = swave[0] + swave[1] + swave[2] + swave[3];
}

// ---------------------------------------------------------------------------
// 9. dueling head
// ---------------------------------------------------------------------------
__global__ void k_head(const float* __restrict__ g,
                       const float* __restrict__ aW1, const float* __restrict__ ab1,
                       const float* __restrict__ aW2, const float* __restrict__ ab2,
                       const float* __restrict__ vW1, const float* __restrict__ vb1,
                       const float* __restrict__ vW2, const float* __restrict__ vb2,
                       float* __restrict__ out) {
    __shared__ float sg[D], t1[D], t2[D], A[ACT], V, meanA;
    int t = threadIdx.x;
    if (t < D) sg[t] = g[t];
    __syncthreads();
    if (t < D) {
        float a = ab1[t], v = vb1[t];
        for (int k = 0; k < D; ++k) {
            a += sg[k] * aW1[k * D + t];
            v += sg[k] * vW1[k * D + t];
        }
        t1[t] = a > 0.f ? a : 0.f;
        t2[t] = v > 0.f ? v : 0.f;
    }
    __syncthreads();
    if (t < ACT) {
        float a = ab2[t];
        for (int d = 0; d < D; ++d) a += t1[d] * aW2[d * ACT + t];
        A[t] = a;
    }
    if (t == D) {
        float v = vb2[0];
        for (int d = 0; d < D; ++d) v += t2[d] * vW2[d];
        V = v;
    }
    __syncthreads();
    if (t == 0) {
        float s = 0.f;
        for (int j = 0; j < ACT; ++j) s += A[j];
        meanA = s / ACT;
    }
    __syncthreads();
    if (t < ACT) out[t] = V + A[t] - meanA;
}

extern "C" void kernel_launch(void* const* d_in, const int* in_sizes, int n_in,
                              void* d_out, int out_size, void* d_ws, size_t ws_size,
                              hipStream_t stream) {
    const float* x      = (const float*)d_in[0];
    const int*   ei     = (const int*)d_in[1];
    // d_in[2] edge_attr: unused by the reference
    const float* gcn_W  = (const float*)d_in[3];
    const float* gcn_b  = (const float*)d_in[4];
    const float* gat_W  = (const float*)d_in[5];
    const float* att_s  = (const float*)d_in[6];
    const float* att_d  = (const float*)d_in[7];
    const float* gat_b  = (const float*)d_in[8];
    const float* aW1    = (const float*)d_in[9];
    const float* ab1    = (const float*)d_in[10];
    const float* aW2    = (const float*)d_in[11];
    const float* ab2    = (const float*)d_in[12];
    const float* vW1    = (const float*)d_in[13];
    const float* vb1    = (const float*)d_in[14];
    const float* vW2    = (const float*)d_in[15];
    const float* vb2    = (const float*)d_in[16];

    const int n = in_sizes[0] / D;       // 100000
    const int e = in_sizes[1] / 2;       // 3200000
    const int* src = ei;
    const int* dst = ei + e;

    const int B = 256;
    const int nb_n = (n + B - 1) / B;
    const int nb_q = (n + (B / 4) - 1) / (B / 4);   // 4 lanes/node
    const int nb_o = (n + (B / 8) - 1) / (B / 8);   // 8 lanes/node
    const int PB   = (nb_o + 63) & ~63;             // padded partials stride
    const int NBA  = 256;                           // binning blocks
    const int nbuk_used = (n + 255) >> 8;           // 391

    // workspace layout
    float* ws       = (float*)d_ws;
    float* h1p      = ws;                                // N*24
    float* h2p      = h1p + (size_t)n * PSTRIDE;         // N*24
    float* g        = h2p + (size_t)n * PSTRIDE;         // 32 (padded)
    float* partials = g + 32;                            // D*PB
    int*   off      = (int*)(partials + (size_t)D * PB); // N+1
    int*   bkt      = off + n + 1;                       // NBUK
    int*   bbase    = bkt + NBUK;                        // NBUK+1
    int*   bcur     = bbase + NBUK + 1;                  // NBUK
    int*   esrc     = bcur + NBUK;                       // E
    unsigned* tmp   = (unsigned*)h1p;                    // E (aliases h1p/h2p head;
                                                         //    dead before k_xw runs)

    hipMemsetAsync(bkt, 0, NBUK * sizeof(int), stream);

    k_bhist<<<256, B, 0, stream>>>(dst, bkt, e);
    k_bscan<<<1, 64, 0, stream>>>(bkt, bbase, bcur, &off[n], e);
    k_bin<<<NBA, B, 0, stream>>>(src, dst, bcur, tmp, e, NBA);
    k_scatter2<<<nbuk_used, B, 0, stream>>>(tmp, bbase, off, esrc, n);
    k_xw<<<nb_n, B, 0, stream>>>(x, gcn_W, off, h1p, n);
    k_gcn_gat<<<nb_q, B, 0, stream>>>(off, esrc, h1p, gcn_b, gat_W,
                                      att_s, att_d, h2p, n);
    k_gat_agg<<<nb_o, B, 0, stream>>>(off, esrc, h2p, gat_b, partials, PB, n);
    k_reduce<<<D, B, 0, stream>>>(partials, PB, nb_o, g);
    k_head<<<1, 64, 0, stream>>>(g, aW1, ab1, aW2, ab2, vW1, vb1, vW2, vb2,
                                 (float*)d_out);
}

// Round 7
// 232.098 us; speedup vs baseline: 13.5411x; 1.1741x over previous
//
#include <hip/hip_runtime.h>

#define D 20
#define ACT 5
#define NEG_SLOPE 0.2f
#define NBUK 512     // dst buckets of 256 nodes (dst >> 8)

__device__ __forceinline__ float leaky(float x) {
    return x > 0.f ? x : NEG_SLOPE * x;
}

// ---- bf16x2 packing (RNE) ----
__device__ __forceinline__ unsigned pack_bf16x2(float a, float b) {
    unsigned ua = __float_as_uint(a);
    unsigned ub = __float_as_uint(b);
    ua += 0x7fffu + ((ua >> 16) & 1u);
    ub += 0x7fffu + ((ub >> 16) & 1u);
    return (ua >> 16) | (ub & 0xffff0000u);
}
__device__ __forceinline__ float blo(unsigned u) { return __uint_as_float(u << 16); }
__device__ __forceinline__ float bhi(unsigned u) { return __uint_as_float(u & 0xffff0000u); }

// acc[d] += w * row[d]  (row = 10 bf16x2 dwords in a.xyzw, b.xyzw, c.x, c.y)
__device__ __forceinline__ void acc_row(float* acc, uint4 a, uint4 b, uint4 c, float w) {
    acc[0]  += w * blo(a.x); acc[1]  += w * bhi(a.x);
    acc[2]  += w * blo(a.y); acc[3]  += w * bhi(a.y);
    acc[4]  += w * blo(a.z); acc[5]  += w * bhi(a.z);
    acc[6]  += w * blo(a.w); acc[7]  += w * bhi(a.w);
    acc[8]  += w * blo(b.x); acc[9]  += w * bhi(b.x);
    acc[10] += w * blo(b.y); acc[11] += w * bhi(b.y);
    acc[12] += w * blo(b.z); acc[13] += w * bhi(b.z);
    acc[14] += w * blo(b.w); acc[15] += w * bhi(b.w);
    acc[16] += w * blo(c.x); acc[17] += w * bhi(c.x);
    acc[18] += w * blo(c.y); acc[19] += w * bhi(c.y);
}
// acc[d] = acc[d]*cs + w * row[d]   (online-softmax update)
__device__ __forceinline__ void fma_row(float* acc, uint4 a, uint4 b, uint4 c,
                                        float cs, float w) {
    acc[0]  = acc[0]  * cs + w * blo(a.x); acc[1]  = acc[1]  * cs + w * bhi(a.x);
    acc[2]  = acc[2]  * cs + w * blo(a.y); acc[3]  = acc[3]  * cs + w * bhi(a.y);
    acc[4]  = acc[4]  * cs + w * blo(a.z); acc[5]  = acc[5]  * cs + w * bhi(a.z);
    acc[6]  = acc[6]  * cs + w * blo(a.w); acc[7]  = acc[7]  * cs + w * bhi(a.w);
    acc[8]  = acc[8]  * cs + w * blo(b.x); acc[9]  = acc[9]  * cs + w * bhi(b.x);
    acc[10] = acc[10] * cs + w * blo(b.y); acc[11] = acc[11] * cs + w * bhi(b.y);
    acc[12] = acc[12] * cs + w * blo(b.z); acc[13] = acc[13] * cs + w * bhi(b.z);
    acc[14] = acc[14] * cs + w * blo(b.w); acc[15] = acc[15] * cs + w * bhi(b.w);
    acc[16] = acc[16] * cs + w * blo(c.x); acc[17] = acc[17] * cs + w * bhi(c.x);
    acc[18] = acc[18] * cs + w * blo(c.y); acc[19] = acc[19] * cs + w * bhi(c.y);
}

// ---------------------------------------------------------------------------
// 1. bucket histogram of dst (512 buckets, LDS-aggregated, int4 loads)
// ---------------------------------------------------------------------------
__global__ void k_bhist(const int* __restrict__ dst, int* __restrict__ bkt, int e) {
    __shared__ int lh[NBUK];
    for (int b = threadIdx.x; b < NBUK; b += blockDim.x) lh[b] = 0;
    __syncthreads();
    int stride = gridDim.x * blockDim.x;
    int tid = blockIdx.x * blockDim.x + threadIdx.x;
    int n4 = e >> 2;
    const int4* d4 = (const int4*)dst;
    for (int i = tid; i < n4; i += stride) {
        int4 v = d4[i];
        atomicAdd(&lh[v.x >> 8], 1);
        atomicAdd(&lh[v.y >> 8], 1);
        atomicAdd(&lh[v.z >> 8], 1);
        atomicAdd(&lh[v.w >> 8], 1);
    }
    for (int i = (n4 << 2) + tid; i < e; i += stride)
        atomicAdd(&lh[dst[i] >> 8], 1);
    __syncthreads();
    for (int b = threadIdx.x; b < NBUK; b += blockDim.x) {
        int c = lh[b];
        if (c) atomicAdd(&bkt[b], c);
    }
}

// ---------------------------------------------------------------------------
// 2. single-block scan of bucket counts -> bbase[513], bcur; off[n] = e
// ---------------------------------------------------------------------------
__global__ void k_bscan(const int* __restrict__ bkt, int* __restrict__ bbase,
                        int* __restrict__ bcur, int* __restrict__ off_n, int e) {
    if (threadIdx.x == 0) {
        int run = 0;
        for (int k = 0; k < NBUK; ++k) {
            bbase[k] = run; bcur[k] = run; run += bkt[k];
        }
        bbase[NBUK] = run;
        *off_n = e;
    }
}

// ---------------------------------------------------------------------------
// 3. bin edges by dst bucket into tmp (packed src<<8 | dst&255)
// ---------------------------------------------------------------------------
__global__ void k_bin(const int* __restrict__ src, const int* __restrict__ dst,
                      int* __restrict__ bcur, unsigned* __restrict__ tmp,
                      int e, int nba) {
    __shared__ int lh[NBUK];
    for (int b = threadIdx.x; b < NBUK; b += blockDim.x) lh[b] = 0;
    __syncthreads();
    int chunk = (e + nba - 1) / nba;
    int lo = blockIdx.x * chunk, hi = min(lo + chunk, e);
    for (int j = lo + threadIdx.x; j < hi; j += blockDim.x)
        atomicAdd(&lh[dst[j] >> 8], 1);
    __syncthreads();
    for (int b = threadIdx.x; b < NBUK; b += blockDim.x) {
        int c = lh[b];
        lh[b] = c ? atomicAdd(&bcur[b], c) : 0;
    }
    __syncthreads();
    for (int j = lo + threadIdx.x; j < hi; j += blockDim.x) {
        int t = dst[j];
        int p = atomicAdd(&lh[t >> 8], 1);
        tmp[p] = ((unsigned)src[j] << 8) | (unsigned)(t & 255);
    }
}

// ---------------------------------------------------------------------------
// 4. per-bucket: LDS node histogram + block scan -> off[]; LDS-cursor scatter
// ---------------------------------------------------------------------------
__global__ void k_scatter2(const unsigned* __restrict__ tmp, const int* __restrict__ bbase,
                           int* __restrict__ off, int* __restrict__ esrc, int n) {
    __shared__ int ldeg[256];
    __shared__ int lcur[256];
    __shared__ int wtot[4];
    int b = blockIdx.x;
    int t = threadIdx.x;
    int nlo = b << 8;
    int nloc = min(nlo + 256, n) - nlo;       // nodes in this bucket
    int lo = bbase[b], hi = bbase[b + 1];

    ldeg[t] = 0;
    __syncthreads();
    for (int i = lo + t; i < hi; i += blockDim.x)
        atomicAdd(&ldeg[tmp[i] & 255u], 1);
    __syncthreads();

    // exclusive block scan of ldeg
    int v = ldeg[t];
    int lane = t & 63, wv = t >> 6;
    int s = v;
    for (int o = 1; o < 64; o <<= 1) {
        int u = __shfl_up(s, o);
        if (lane >= o) s += u;
    }
    if (lane == 63) wtot[wv] = s;
    __syncthreads();
    int wb = 0;
    for (int k = 0; k < wv; ++k) wb += wtot[k];
    int pos = lo + wb + s - v;                // exclusive prefix + bucket base
    if (t < nloc) off[nlo + t] = pos;
    lcur[t] = pos;
    __syncthreads();

    for (int i = lo + t; i < hi; i += blockDim.x) {
        unsigned w = tmp[i];
        int p = atomicAdd(&lcur[w & 255u], 1);
        esrc[p] = (int)(w >> 8);
    }
}

// ---------------------------------------------------------------------------
// 5. h1b row i (64-B aligned): d0..d9 = bf16x2(x@gcn_W), d10 = fp32 dinv
// ---------------------------------------------------------------------------
__global__ void k_xw(const float* __restrict__ x, const float* __restrict__ W,
                     const int* __restrict__ off, uint4* __restrict__ h1b, int n) {
    __shared__ float sW[D * D];
    for (int t = threadIdx.x; t < D * D; t += blockDim.x) sW[t] = W[t];
    __syncthreads();
    int i = blockIdx.x * blockDim.x + threadIdx.x;
    if (i >= n) return;
    float xi[D];
    const float4* xr = (const float4*)(x + (size_t)i * D);
#pragma unroll
    for (int q = 0; q < D / 4; ++q) {
        float4 v = xr[q];
        xi[4 * q + 0] = v.x; xi[4 * q + 1] = v.y;
        xi[4 * q + 2] = v.z; xi[4 * q + 3] = v.w;
    }
    unsigned dw[12];
#pragma unroll
    for (int p = 0; p < 10; ++p) {
        float h0 = 0.f, h1 = 0.f;
#pragma unroll
        for (int k = 0; k < D; ++k) {
            h0 += xi[k] * sW[k * D + 2 * p];
            h1 += xi[k] * sW[k * D + 2 * p + 1];
        }
        dw[p] = pack_bf16x2(h0, h1);
    }
    int dg = off[i + 1] - off[i];
    dw[10] = __float_as_uint(rsqrtf((float)(dg + 1)));
    dw[11] = 0u;
    uint4* o = h1b + (size_t)i * 4;
    o[0] = make_uint4(dw[0], dw[1], dw[2], dw[3]);
    o[1] = make_uint4(dw[4], dw[5], dw[6], dw[7]);
    o[2] = make_uint4(dw[8], dw[9], dw[10], dw[11]);
}

// ---------------------------------------------------------------------------
// 6. fused GCN gather (4 lanes/node, bf16 rows) + relu + GAT transform
//    h2b row: d0..d9 = bf16x2 h2, d10 = fp32 a_src, d11 = fp32 a_dst
// ---------------------------------------------------------------------------
__global__ void k_gcn_gat(const int* __restrict__ off, const int* __restrict__ esrc,
                          const uint4* __restrict__ h1b, const float* __restrict__ gcn_b,
                          const float* __restrict__ gat_W, const float* __restrict__ att_s,
                          const float* __restrict__ att_d, uint4* __restrict__ h2b, int n) {
    __shared__ float sW[D * D], sb[D], sas[D], sad[D];
    for (int t = threadIdx.x; t < D * D; t += blockDim.x) sW[t] = gat_W[t];
    if (threadIdx.x < D) {
        sb[threadIdx.x]  = gcn_b[threadIdx.x];
        sas[threadIdx.x] = att_s[threadIdx.x];
        sad[threadIdx.x] = att_d[threadIdx.x];
    }
    __syncthreads();
    int t = threadIdx.x;
    int i = blockIdx.x * (blockDim.x >> 2) + (t >> 2);
    int q = t & 3;
    bool valid = i < n;

    float acc[D];
#pragma unroll
    for (int d = 0; d < D; ++d) acc[d] = 0.f;

    if (valid) {
        const uint4* row = h1b + (size_t)i * 4;
        uint4 rc = row[2];
        float di = __uint_as_float(rc.z);
        if (q == 0) {                       // self-loop term
            uint4 ra = row[0], rb = row[1];
            acc_row(acc, ra, rb, rc, di * di);
        }
        int s0 = off[i], s1 = off[i + 1];
        for (int j = s0 + q; j < s1; j += 4) {
            int s = esrc[j];
            const uint4* rs = h1b + (size_t)s * 4;
            uint4 a = rs[0], b = rs[1], c = rs[2];
            acc_row(acc, a, b, c, di * __uint_as_float(c.z));
        }
    }
    // quad all-reduce of acc
#pragma unroll
    for (int d = 0; d < D; ++d) acc[d] += __shfl_xor(acc[d], 1);
#pragma unroll
    for (int d = 0; d < D; ++d) acc[d] += __shfl_xor(acc[d], 2);

    if (valid && q == 0) {                  // lane 0: transform + pack + store
        float v[D];
#pragma unroll
        for (int k = 0; k < D; ++k) {
            float tv = acc[k] + sb[k];
            v[k] = tv > 0.f ? tv : 0.f;
        }
        unsigned dw[12];
        float as_ = 0.f, ad_ = 0.f;
#pragma unroll
        for (int p = 0; p < 10; ++p) {
            float h0 = 0.f, h1 = 0.f;
#pragma unroll
            for (int k = 0; k < D; ++k) {
                h0 += v[k] * sW[k * D + 2 * p];
                h1 += v[k] * sW[k * D + 2 * p + 1];
            }
            as_ += h0 * sas[2 * p] + h1 * sas[2 * p + 1];
            ad_ += h0 * sad[2 * p] + h1 * sad[2 * p + 1];
            dw[p] = pack_bf16x2(h0, h1);
        }
        dw[10] = __float_as_uint(as_);
        dw[11] = __float_as_uint(ad_);
        uint4* o = h2b + (size_t)i * 4;
        o[0] = make_uint4(dw[0], dw[1], dw[2], dw[3]);
        o[1] = make_uint4(dw[4], dw[5], dw[6], dw[7]);
        o[2] = make_uint4(dw[8], dw[9], dw[10], dw[11]);
    }
}

// ---------------------------------------------------------------------------
// 7. GAT online-softmax aggregate, 8 lanes/node, bf16 rows; block partial
//    -> partials[d*PB + block]
// ---------------------------------------------------------------------------
__global__ void k_gat_agg(const int* __restrict__ off, const int* __restrict__ esrc,
                          const uint4* __restrict__ h2b, const float* __restrict__ gat_b,
                          float* __restrict__ partials, int PB, int n) {
    __shared__ float sb[D];
    __shared__ float swave[4][D];
    if (threadIdx.x < D) sb[threadIdx.x] = gat_b[threadIdx.x];
    __syncthreads();
    int t = threadIdx.x;
    int i = blockIdx.x * (blockDim.x >> 3) + (t >> 3);
    int o = t & 7;
    bool valid = i < n;

    float m = -1e30f, den = 0.f;
    float acc[D];
#pragma unroll
    for (int d = 0; d < D; ++d) acc[d] = 0.f;

    if (valid) {
        const uint4* row = h2b + (size_t)i * 4;
        uint4 rc = row[2];
        float ad_i = __uint_as_float(rc.w);
        if (o == 0) {                      // self edge seeds the online softmax
            m = leaky(__uint_as_float(rc.z) + ad_i);
            den = 1.f;
            acc_row(acc, row[0], row[1], rc, 1.0f);
        }
        int s0 = off[i], s1 = off[i + 1];
        for (int j = s0 + o; j < s1; j += 8) {
            int s = esrc[j];
            const uint4* rs = h2b + (size_t)s * 4;
            uint4 a = rs[0], b = rs[1], c = rs[2];
            float eg = leaky(__uint_as_float(c.z) + ad_i);
            float nm = fmaxf(m, eg);
            float cs = __expf(m - nm), w = __expf(eg - nm);
            den = den * cs + w;
            fma_row(acc, a, b, c, cs, w);
            m = nm;
        }
    }
    // octet merge of (m, den, acc)
#pragma unroll
    for (int mask = 1; mask < 8; mask <<= 1) {
        float om = __shfl_xor(m, mask);
        float oden = __shfl_xor(den, mask);
        float nm = fmaxf(m, om);
        float c1 = __expf(m - nm), c2 = __expf(om - nm);
        den = den * c1 + oden * c2;
#pragma unroll
        for (int d = 0; d < D; ++d) {
            float oa = __shfl_xor(acc[d], mask);
            acc[d] = acc[d] * c1 + oa * c2;
        }
        m = nm;
    }
    float inv = den > 0.f ? 1.0f / den : 0.f;
#pragma unroll
    for (int d = 0; d < D; ++d) {
        float vv = acc[d] * inv + sb[d];
        vv = vv > 0.f ? vv : 0.f;
        if (!valid || o != 0) vv = 0.f;    // one contribution per node
        acc[d] = vv;
    }
    int wv = t >> 6, ln = t & 63;
#pragma unroll
    for (int d = 0; d < D; ++d) {
        float vv = acc[d];
        for (int s2 = 32; s2; s2 >>= 1) vv += __shfl_down(vv, s2);
        if (ln == 0) swave[wv][d] = vv;
    }
    __syncthreads();
    if (t < D) {
        float s = swave[0][t] + swave[1][t] + swave[2][t] + swave[3][t];
        partials[(size_t)t * PB + blockIdx.x] = s;
    }
}

// ---------------------------------------------------------------------------
// 8. final readout reduce: one block per channel, no atomics
// ---------------------------------------------------------------------------
__global__ void k_reduce(const float* __restrict__ partials, int PB, int nblk,
                         float* __restrict__ g) {
    __shared__ float swave[4];
    int d = blockIdx.x;
    int t = threadIdx.x;
    const float* p = partials + (size_t)d * PB;
    float s = 0.f;
    for (int i = t; i < nblk; i += blockDim.x) s += p[i];
    for (int s2 = 32; s2; s2 >>= 1) s += __shfl_down(s, s2);
    if ((t & 63) == 0) swave[t >> 6] = s;
    __syncthreads();
    if (t == 0) g[d] = swave[0] + swave[1] + swave[2] + swave[3];
}

// ---------------------------------------------------------------------------
// 9. dueling head
// ---------------------------------------------------------------------------
__global__ void k_head(const float* __restrict__ g,
                       const float* __restrict__ aW1, const float* __restrict__ ab1,
                       const float* __restrict__ aW2, const float* __restrict__ ab2,
                       const float* __restrict__ vW1, const float* __restrict__ vb1,
                       const float* __restrict__ vW2, const float* __restrict__ vb2,
                       float* __restrict__ out) {
    __shared__ float sg[D], t1[D], t2[D], A[ACT], V, meanA;
    int t = threadIdx.x;
    if (t < D) sg[t] = g[t];
    __syncthreads();
    if (t < D) {
        float a = ab1[t], v = vb1[t];
        for (int k = 0; k < D; ++k) {
            a += sg[k] * aW1[k * D + t];
            v += sg[k] * vW1[k * D + t];
        }
        t1[t] = a > 0.f ? a : 0.f;
        t2[t] = v > 0.f ? v : 0.f;
    }
    __syncthreads();
    if (t < ACT) {
        float a = ab2[t];
        for (int d = 0; d < D; ++d) a += t1[d] * aW2[d * ACT + t];
        A[t] = a;
    }
    if (t == D) {
        float v = vb2[0];
        for (int d = 0; d < D; ++d) v += t2[d] * vW2[d];
        V = v;
    }
    __syncthreads();
    if (t == 0) {
        float s = 0.f;
        for (int j = 0; j < ACT; ++j) s += A[j];
        meanA = s / ACT;
    }
    __syncthreads();
    if (t < ACT) out[t] = V + A[t] - meanA;
}

extern "C" void kernel_launch(void* const* d_in, const int* in_sizes, int n_in,
                              void* d_out, int out_size, void* d_ws, size_t ws_size,
                              hipStream_t stream) {
    const float* x      = (const float*)d_in[0];
    const int*   ei     = (const int*)d_in[1];
    // d_in[2] edge_attr: unused by the reference
    const float* gcn_W  = (const float*)d_in[3];
    const float* gcn_b  = (const float*)d_in[4];
    const float* gat_W  = (const float*)d_in[5];
    const float* att_s  = (const float*)d_in[6];
    const float* att_d  = (const float*)d_in[7];
    const float* gat_b  = (const float*)d_in[8];
    const float* aW1    = (const float*)d_in[9];
    const float* ab1    = (const float*)d_in[10];
    const float* aW2    = (const float*)d_in[11];
    const float* ab2    = (const float*)d_in[12];
    const float* vW1    = (const float*)d_in[13];
    const float* vb1    = (const float*)d_in[14];
    const float* vW2    = (const float*)d_in[15];
    const float* vb2    = (const float*)d_in[16];

    const int n = in_sizes[0] / D;       // 100000
    const int e = in_sizes[1] / 2;       // 3200000
    const int* src = ei;
    const int* dst = ei + e;

    const int B = 256;
    const int nb_n = (n + B - 1) / B;
    const int nb_q = (n + (B / 4) - 1) / (B / 4);   // 4 lanes/node
    const int nb_o = (n + (B / 8) - 1) / (B / 8);   // 8 lanes/node
    const int PB   = (nb_o + 63) & ~63;             // padded partials stride
    const int NBA  = 256;                           // binning blocks
    const int nbuk_used = (n + 255) >> 8;           // 391

    // workspace layout
    uint4* h1b      = (uint4*)d_ws;                      // n*4 uint4 (64 B rows)
    uint4* h2b      = h1b + (size_t)n * 4;               // n*4 uint4
    float* g        = (float*)(h2b + (size_t)n * 4);     // 32 (padded)
    float* partials = g + 32;                            // D*PB
    int*   off      = (int*)(partials + (size_t)D * PB); // N+1
    int*   bkt      = off + n + 1;                       // NBUK
    int*   bbase    = bkt + NBUK;                        // NBUK+1
    int*   bcur     = bbase + NBUK + 1;                  // NBUK
    int*   esrc     = bcur + NBUK;                       // E
    unsigned* tmp   = (unsigned*)d_ws;                   // E dwords; aliases h1b+h2b
                                                         // (dead before k_xw runs)

    hipMemsetAsync(bkt, 0, NBUK * sizeof(int), stream);

    k_bhist<<<256, B, 0, stream>>>(dst, bkt, e);
    k_bscan<<<1, 64, 0, stream>>>(bkt, bbase, bcur, &off[n], e);
    k_bin<<<NBA, B, 0, stream>>>(src, dst, bcur, tmp, e, NBA);
    k_scatter2<<<nbuk_used, B, 0, stream>>>(tmp, bbase, off, esrc, n);
    k_xw<<<nb_n, B, 0, stream>>>(x, gcn_W, off, h1b, n);
    k_gcn_gat<<<nb_q, B, 0, stream>>>(off, esrc, h1b, gcn_b, gat_W,
                                      att_s, att_d, h2b, n);
    k_gat_agg<<<nb_o, B, 0, stream>>>(off, esrc, h2b, gat_b, partials, PB, n);
    k_reduce<<<D, B, 0, stream>>>(partials, PB, nb_o, g);
    k_head<<<1, 64, 0, stream>>>(g, aW1, ab1, aW2, ab2, vW1, vb1, vW2, vb2,
                                 (float*)d_out);
}